// Round 5
// baseline (377.360 us; speedup 1.0000x reference)
//
#include <hip/hip_runtime.h>
#include <hip/hip_bf16.h>

typedef _Float16 half8 __attribute__((ext_vector_type(8)));
typedef _Float16 half4v __attribute__((ext_vector_type(4)));
typedef float floatx4 __attribute__((ext_vector_type(4)));
typedef float floatx16 __attribute__((ext_vector_type(16)));

// ---------------------------------------------------------------------------
// R21: wave tile 64x128 (2m x 4n, acc=128), BM=128, 4-wave blocks (wave w:
// rows (w>>1)*64, cols (w&1)*128), 2 blocks/CU. Rationale: R16/R18/R19/R20
// all pin at 44-45% MfmaUtil / ~264us with IDENTICAL per-kstep instruction
// counts (4 A ds_read_b128 + 2 W vmem per wave). Serial per-CU accounting
// (matrix 61.5K + LDS 47K + vmem ~20K + misc 20K cy/gen ~= measured 158K)
// says the binder is delivery-instruction throughput, not scheduling. 64x128
// HALVES the LDS-A reads per MFMA (2 reads : 8 MFMA) and moves the extra
// delivery to the vmem path (4 W loads/kstep, L1/L2-resident, no LDS-unit
// contention). x-staging vectorized to half8 LDS writes (the 9.3M
// SQ_LDS_BANK_CONFLICT was the scalar 2-B staging stores, not the K-loop).
//
// Act layout: chunk-major, 128-row chunks:
//   off(row, col) = (col>>3)*1024 + row*8 + (col&7)   [halfs]
// A-frag (ks, mi): base = lhi*1024 + ((wr*64)+l31)*8, imm = ks*4096 +
// mi*512 B (max 15*4096+512 < 64KiB ds-imm; L5 ks>=16 -> x buffer).
// LDS: act 128x256 fp16 (64 KiB, in-place) + x 128x48 (12 KiB) = 76 KiB.
// __launch_bounds__(256,2): 256-reg cap (acc 128 + W-ring 64 + ~50 arch).
// ---------------------------------------------------------------------------
__device__ __forceinline__ int cmaj(int row, int col) {
    return ((col >> 3) << 10) + (row << 3) + (col & 7);
}

// ---------------------------------------------------------------------------
// Weight pre-pack (unchanged, proven R5-R20): fp32 (K,N) row-major -> fp16
// fragment order; lane L holds W[kt*16 + 8*(L>>5) + j][nt*32 + (L&31)].
// Fed to the MFMA *A* operand so D = C^T. K zero-padded: L1 39->64 (KT=4),
// L5 295->320 (KT=20), others 256 (KT=16). L9 N 4->32. Tile starts (1KB):
// {0,32,160,288,416,576,704,832,960}, total 976 tiles = 999424 B in d_ws.
// ---------------------------------------------------------------------------
__global__ void pack_w32(const float* __restrict__ w1, const float* __restrict__ w2,
                         const float* __restrict__ w3, const float* __restrict__ w4,
                         const float* __restrict__ w5, const float* __restrict__ w6,
                         const float* __restrict__ w7, const float* __restrict__ w8,
                         const float* __restrict__ w9, _Float16* __restrict__ dst) {
    const int tileStart[10] = {0, 32, 160, 288, 416, 576, 704, 832, 960, 976};
    const int Ks[9] = {39, 256, 256, 256, 295, 256, 256, 256, 256};
    const int Ns[9] = {256, 256, 256, 256, 256, 256, 256, 256, 4};
    const int Tn[9] = {8, 8, 8, 8, 8, 8, 8, 8, 1};
    const float* ws[9] = {w1, w2, w3, w4, w5, w6, w7, w8, w9};

    int g = blockIdx.x * blockDim.x + threadIdx.x;
    int tile = g >> 6, lane = g & 63;
    if (tile >= 976) return;
    int layer = 0;
    while (tile >= tileStart[layer + 1]) layer++;
    int t = tile - tileStart[layer];
    int tn = Tn[layer];
    int kt = t / tn, nt = t - kt * tn;
    int k0 = kt * 16 + (lane >> 5) * 8;
    int n = nt * 32 + (lane & 31);
    const float* w = ws[layer];
    int K = Ks[layer], N = Ns[layer];
    _Float16 v[8];
#pragma unroll
    for (int j = 0; j < 8; j++) {
        int k = k0 + j;
        v[j] = (k < K && n < N) ? (_Float16)w[k * N + n] : (_Float16)0.f;
    }
    *(half8*)(dst + (size_t)tile * 512 + lane * 8) = *(half8*)v;
}

// A-fragment read: single base + immediate offset (halfs): s*2048 + mi*256.
// FROMX selects the x-buffer (XOFF = first x kstep) at compile time.
template <bool FROMX, int XOFF>
__device__ __forceinline__ half8 rdA(const _Float16* aB, const _Float16* xB,
                                     int s, int mi) {
    if (FROMX) return *(const half8*)(xB + (s - XOFF) * 2048 + mi * 256);
    return *(const half8*)(aB + s * 2048 + mi * 256);
}

// Two k-steps: 4 ds_read_b128 + 16 MFMA, W frags already resident (no copies).
template <bool FROMX, int XOFF>
__device__ __forceinline__ void two_steps(const _Float16* aB, const _Float16* xB,
                                          int ks,
                                          const half8 (&wA)[4],   // step ks
                                          const half8 (&wB)[4],   // step ks+1
                                          floatx16 (&acc)[2][4]) {
    half8 a0 = rdA<FROMX, XOFF>(aB, xB, ks, 0);
    half8 a1 = rdA<FROMX, XOFF>(aB, xB, ks, 1);
    half8 b0 = rdA<FROMX, XOFF>(aB, xB, ks + 1, 0);
    half8 b1 = rdA<FROMX, XOFF>(aB, xB, ks + 1, 1);
    __builtin_amdgcn_s_setprio(1);
#pragma unroll
    for (int ni = 0; ni < 4; ni++) {
        acc[0][ni] = __builtin_amdgcn_mfma_f32_32x32x16_f16(wA[ni], a0, acc[0][ni], 0, 0, 0);
        acc[1][ni] = __builtin_amdgcn_mfma_f32_32x32x16_f16(wA[ni], a1, acc[1][ni], 0, 0, 0);
    }
#pragma unroll
    for (int ni = 0; ni < 4; ni++) {
        acc[0][ni] = __builtin_amdgcn_mfma_f32_32x32x16_f16(wB[ni], b0, acc[0][ni], 0, 0, 0);
        acc[1][ni] = __builtin_amdgcn_mfma_f32_32x32x16_f16(wB[ni], b1, acc[1][ni], 0, 0, 0);
    }
    __builtin_amdgcn_s_setprio(0);
}

// One k-step (odd tails): 2 ds_read_b128 + 8 MFMA.
template <bool FROMX, int XOFF>
__device__ __forceinline__ void one_step(const _Float16* aB, const _Float16* xB,
                                         int ks, const half8 (&wA)[4],
                                         floatx16 (&acc)[2][4]) {
    half8 a0 = rdA<FROMX, XOFF>(aB, xB, ks, 0);
    half8 a1 = rdA<FROMX, XOFF>(aB, xB, ks, 1);
    __builtin_amdgcn_s_setprio(1);
#pragma unroll
    for (int ni = 0; ni < 4; ni++) {
        acc[0][ni] = __builtin_amdgcn_mfma_f32_32x32x16_f16(wA[ni], a0, acc[0][ni], 0, 0, 0);
        acc[1][ni] = __builtin_amdgcn_mfma_f32_32x32x16_f16(wA[ni], a1, acc[1][ni], 0, 0, 0);
    }
    __builtin_amdgcn_s_setprio(0);
}

// ---------------------------------------------------------------------------
// One fused layer: C(128x256) = relu(A(128xK) @ W + b), in-place LDS->LDS.
// Wave tile 64x128: per kstep 2 A-frags (ds_read_b128, shared across 4
// n-frags) + 4 W-frags (global 16B, L2-resident) + 8 MFMA. 2-deep no-copy
// W ring (4-frag sets). AMODE 0: act. 1: ksteps >= KS0 from x (L5 skip,
// KS0 == KMAIN). 2: entirely x (L1).
// ---------------------------------------------------------------------------
template <int KT, int AMODE, int KS0>
__device__ __forceinline__ void layerT(const _Float16* abuf,
                                       const _Float16* __restrict__ xbuf,
                                       const half8* __restrict__ wq,
                                       const float* __restrict__ bias,
                                       _Float16* obuf,
                                       int lane, int wave) {
    constexpr int KTAIL = (KT % 4 == 0) ? 4 : (KT % 4);
    constexpr int KMAIN = KT - KTAIL;
    static_assert(KTAIL == 4 || KTAIL == 3, "tail must be 3 or 4 ksteps");
    static_assert(AMODE != 1 || KS0 == KMAIN, "L5 x-switch must align with tail");
    constexpr bool MX = (AMODE == 2);   // main loop reads x?
    constexpr bool TX = (AMODE != 0);   // tail reads x?
    constexpr int TOFF = (AMODE == 1) ? KS0 : 0;

    const int l31 = lane & 31, lhi = lane >> 5;
    const int wr = wave >> 1, wc = wave & 1;   // row-half / col-half of block
    const _Float16* aBase = abuf + lhi * 1024 + (wr * 64 + l31) * 8;
    const _Float16* xBase = xbuf + lhi * 1024 + (wr * 64 + l31) * 8;
    // W frag (kstep ks, n-tile wc*4+ni): wl[ks*512 + ni*64]
    const half8* wl = wq + (wc * 4) * 64 + lane;
    auto ldW4 = [&](int s, half8 (&w)[4]) {
#pragma unroll
        for (int ni = 0; ni < 4; ni++) w[ni] = wl[s * 512 + ni * 64];
    };

    // Bias -> acc init: acc element g*4+r is channel wc*128 + ni*32 + lhi*4 + g*8 + r.
    floatx16 acc[2][4];
#pragma unroll
    for (int ni = 0; ni < 4; ni++) {
        floatx16 t;
#pragma unroll
        for (int g = 0; g < 4; g++) {
            floatx4 b = *(const floatx4*)(bias + wc * 128 + ni * 32 + g * 8 + lhi * 4);
#pragma unroll
            for (int r = 0; r < 4; r++) t[g * 4 + r] = b[r];
        }
        acc[0][ni] = t;
        acc[1][ni] = t;
    }

    // 2-deep no-copy W ring (4-frag sets; R19-proven structure).
    half8 w0[4], w1[4], w2[4], w3[4];
    ldW4(0, w0);
    ldW4(1, w1);
#pragma unroll 1
    for (int ks = 0; ks < KMAIN; ks += 4) {
        ldW4(ks + 2, w2);
        ldW4(ks + 3, w3);
        two_steps<MX, 0>(aBase, xBase, ks, w0, w1, acc);
        ldW4(ks + 4, w0);
        ldW4(ks + 5, w1);
        two_steps<MX, 0>(aBase, xBase, ks + 2, w2, w3, acc);
    }
    if constexpr (KTAIL == 4) {
        ldW4(KT - 2, w2);
        ldW4(KT - 1, w3);
        two_steps<TX, TOFF>(aBase, xBase, KMAIN, w0, w1, acc);
        two_steps<TX, TOFF>(aBase, xBase, KMAIN + 2, w2, w3, acc);
    } else {  // KTAIL == 3
        ldW4(KT - 1, w2);
        two_steps<TX, TOFF>(aBase, xBase, KMAIN, w0, w1, acc);
        one_step<TX, TOFF>(aBase, xBase, KMAIN + 2, w2, acc);
    }

    // relu + fp16 cvt into regs BEFORE the barrier (shrink serialized tail).
    half4v hv[2][4][4];
#pragma unroll
    for (int mi = 0; mi < 2; mi++)
#pragma unroll
        for (int ni = 0; ni < 4; ni++)
#pragma unroll
            for (int g = 0; g < 4; g++) {
                half4v h;
#pragma unroll
                for (int r = 0; r < 4; r++) {
                    float v = acc[mi][ni][g * 4 + r];
                    v = v > 0.f ? v : 0.f;
                    h[r] = (_Float16)v;
                }
                hv[mi][ni][g] = h;
            }

    // In-place safety barrier: all waves' act-reads complete before any write.
    if (AMODE != 2) __syncthreads();
    // row = wr*64 + mi*32 + l31; col = wc*128 + ni*32 + g*8 + lhi*4 + r
    // -> chunk = wc*16 + ni*4 + g, inner = lhi*4 + r.
#pragma unroll
    for (int mi = 0; mi < 2; mi++) {
        _Float16* ob = obuf + (wr * 64 + mi * 32 + l31) * 8 + lhi * 4;
#pragma unroll
        for (int ni = 0; ni < 4; ni++)
#pragma unroll
            for (int g = 0; g < 4; g++)
                *(half4v*)(ob + (wc * 16 + ni * 4 + g) * 1024) = hv[mi][ni][g];
    }
}

// Layer 9 (swapped): 256 -> 4 (N padded to 32). Each of 4 waves takes one
// 32-row m-frag; dual accumulators break the serial MFMA chain.
__device__ __forceinline__ void layer9T(const _Float16* abuf,
                                        const half8* __restrict__ wq,
                                        const float* __restrict__ b9,
                                        float* __restrict__ out, long r0,
                                        int lane, int wave) {
    const int l31 = lane & 31, lhi = lane >> 5;
    const _Float16* aBase = abuf + lhi * 1024 + (wave * 32 + l31) * 8;
    floatx16 acc_e = {}, acc_o = {};
    const half8* wl = wq + lane;
#pragma unroll
    for (int ks = 0; ks < 16; ks += 2) {
        half8 we = wl[ks * 64], wo = wl[(ks + 1) * 64];
        half8 ae = *(const half8*)(aBase + ks * 2048);
        half8 ao = *(const half8*)(aBase + (ks + 1) * 2048);
        acc_e = __builtin_amdgcn_mfma_f32_32x32x16_f16(we, ae, acc_e, 0, 0, 0);
        acc_o = __builtin_amdgcn_mfma_f32_32x32x16_f16(wo, ao, acc_o, 0, 0, 0);
    }
    if (lhi == 0) {
        floatx4 b4 = *(const floatx4*)(b9);
        floatx4 o;
#pragma unroll
        for (int r = 0; r < 4; r++) o[r] = acc_e[r] + acc_o[r] + b4[r];
        *(floatx4*)(out + (r0 + wave * 32 + l31) * 4) = o;
    }
}

__global__ __launch_bounds__(256, 2) void mlp_fused(
    const float* __restrict__ x, const _Float16* __restrict__ wpk,
    const float* __restrict__ b1, const float* __restrict__ b2,
    const float* __restrict__ b3, const float* __restrict__ b4,
    const float* __restrict__ b5, const float* __restrict__ b6,
    const float* __restrict__ b7, const float* __restrict__ b8,
    const float* __restrict__ b9, float* __restrict__ out) {
    // act 128x256 fp16 (64 KiB, in-place) + x 128x48 (12 KiB) = 76 KiB;
    // 4-wave blocks; 2 blocks/CU = 8 waves/CU = 2 waves/SIMD (256-reg cap).
    __shared__ _Float16 lds[128 * 256 + 128 * 48];
    _Float16* buf = lds;
    _Float16* xbuf = lds + 128 * 256;
    const int tid = threadIdx.x;
    const int lane = tid & 63, wave = tid >> 6;
    const long r0 = (long)blockIdx.x * 128;

    // Stage x (chunk-major), VECTORIZED: one half8 LDS write per (row,chunk).
    // 128 rows x 6 chunks; cols 39..47 zero-padded. Kills the scalar-store
    // bank conflicts (the 9.3M SQ_LDS_BANK_CONFLICT was this prologue).
    for (int i = tid; i < 128 * 6; i += 256) {
        int row = i / 6, c = i - row * 6;
        const float* xr = x + (r0 + row) * 39 + c * 8;
        _Float16 v[8];
#pragma unroll
        for (int j = 0; j < 8; j++) {
            int col = c * 8 + j;
            v[j] = (col < 39) ? (_Float16)xr[j] : (_Float16)0.f;
        }
        *(half8*)(xbuf + c * 1024 + row * 8) = *(half8*)v;
    }
    __syncthreads();

    const half8* wp = (const half8*)wpk;  // tile = 64 half8 (1 KB)
    const half8* w1q = wp + (size_t)0 * 64;
    const half8* w2q = wp + (size_t)32 * 64;
    const half8* w3q = wp + (size_t)160 * 64;
    const half8* w4q = wp + (size_t)288 * 64;
    const half8* w5q = wp + (size_t)416 * 64;
    const half8* w6q = wp + (size_t)576 * 64;
    const half8* w7q = wp + (size_t)704 * 64;
    const half8* w8q = wp + (size_t)832 * 64;
    const half8* w9q = wp + (size_t)960 * 64;

    layerT<3, 2, 0>(xbuf, xbuf, w1q, b1, buf, lane, wave);   // x -> buf (K=48)
    __syncthreads();
    layerT<16, 0, 0>(buf, xbuf, w2q, b2, buf, lane, wave);
    __syncthreads();
    layerT<16, 0, 0>(buf, xbuf, w3q, b3, buf, lane, wave);
    __syncthreads();
    layerT<16, 0, 0>(buf, xbuf, w4q, b4, buf, lane, wave);
    __syncthreads();
    layerT<19, 1, 16>(buf, xbuf, w5q, b5, buf, lane, wave);  // [h|x] skip, K=304
    __syncthreads();
    layerT<16, 0, 0>(buf, xbuf, w6q, b6, buf, lane, wave);
    __syncthreads();
    layerT<16, 0, 0>(buf, xbuf, w7q, b7, buf, lane, wave);
    __syncthreads();
    layerT<16, 0, 0>(buf, xbuf, w8q, b8, buf, lane, wave);
    __syncthreads();
    layer9T(buf, w9q, b9, out, r0, lane, wave);
}

extern "C" void kernel_launch(void* const* d_in, const int* in_sizes, int n_in,
                              void* d_out, int out_size, void* d_ws, size_t ws_size,
                              hipStream_t stream) {
    const float* x = (const float*)d_in[0];
    const float* w[9];
    const float* b[9];
    for (int i = 0; i < 9; i++) {
        w[i] = (const float*)d_in[1 + 2 * i];
        b[i] = (const float*)d_in[2 + 2 * i];
    }
    _Float16* wpk = (_Float16*)d_ws;  // 999424 B

    pack_w32<<<244, 256, 0, stream>>>(w[0], w[1], w[2], w[3], w[4], w[5], w[6], w[7], w[8], wpk);
    mlp_fused<<<262144 / 128, 256, 0, stream>>>(x, wpk, b[0], b[1], b[2], b[3], b[4],
                                                b[5], b[6], b[7], b[8], (float*)d_out);
}

// Round 6
// 377.110 us; speedup vs baseline: 1.0007x; 1.0007x over previous
//
#include <hip/hip_runtime.h>
#include <hip/hip_bf16.h>

typedef _Float16 half8 __attribute__((ext_vector_type(8)));
typedef _Float16 half4v __attribute__((ext_vector_type(4)));
typedef float floatx4 __attribute__((ext_vector_type(4)));
typedef float floatx16 __attribute__((ext_vector_type(16)));

// ---------------------------------------------------------------------------
// R22: ANTI-PHASE schedule. One 512-thread block (8 waves) per CU, BM=256,
// wave tile 128x64 (4m x 2n, acc=128). Waves split into 2 groups
// (grp = wave>>2); wave i lands on SIMD i&3, so each SIMD hosts exactly one
// wave of each group. Per kstep, two barrier-bounded halves:
//   halfA: g0 MFMA(k)        | g1 LOAD(k+1)
//   halfB: g0 LOAD(k+2)      | g1 MFMA(k)
// => at any instant each SIMD has exactly one wave in its MFMA phase
// (8 MFMA = 256 cy) and one loading. This attacks the R16..R21 plateau
// (44-45% MfmaUtil across ALL schedules at 2-4 waves/SIMD): co-resident
// waves run identical code and phase-lock (both in load/wait windows
// together), which intra-wave pipelining (R20: neutral) cannot fix.
// Load->use distance: g1 = 1 full half (~256cy+bar), g0 = 3 halves; both
// cover LDS (~120cy) and L2-W (~300cy) latency.
//
// Act layout: chunk-major, 256-row chunks:
//   off(row, col) = (col>>3)*2048 + row*8 + (col&7)   [halfs]
// LDS: act 256x256 fp16 (128 KiB, in-place) + x 256x48 (24 KiB) = 152 KiB
// (single block/CU; 128 KiB static precedent: learn_hip m201; arch max 160K).
// __launch_bounds__(512,2): 256-reg cap; need ~90 arch + 128 acc.
// Grid 1024 blocks = 4 sequential gens per CU.
// ---------------------------------------------------------------------------

__device__ __forceinline__ floatx16 MF(half8 w, half8 a, floatx16 c) {
    return __builtin_amdgcn_mfma_f32_32x32x16_f16(w, a, c, 0, 0, 0);
}

#define BAR()                                    \
    do {                                         \
        __builtin_amdgcn_sched_barrier(0);       \
        __builtin_amdgcn_s_barrier();            \
        __builtin_amdgcn_sched_barrier(0);       \
    } while (0)

// ---------------------------------------------------------------------------
// Weight pre-pack (unchanged, proven R5-R21): fp32 (K,N) row-major -> fp16
// fragment order; lane L holds W[kt*16 + 8*(L>>5) + j][nt*32 + (L&31)].
// Fed to the MFMA *A* operand so D = C^T. K zero-padded: L1 39->64 (KT=4),
// L5 295->320 (KT=20), others 256 (KT=16). L9 N 4->32. Tile starts (1KB):
// {0,32,160,288,416,576,704,832,960}, total 976 tiles = 999424 B in d_ws.
// ---------------------------------------------------------------------------
__global__ void pack_w32(const float* __restrict__ w1, const float* __restrict__ w2,
                         const float* __restrict__ w3, const float* __restrict__ w4,
                         const float* __restrict__ w5, const float* __restrict__ w6,
                         const float* __restrict__ w7, const float* __restrict__ w8,
                         const float* __restrict__ w9, _Float16* __restrict__ dst) {
    const int tileStart[10] = {0, 32, 160, 288, 416, 576, 704, 832, 960, 976};
    const int Ks[9] = {39, 256, 256, 256, 295, 256, 256, 256, 256};
    const int Ns[9] = {256, 256, 256, 256, 256, 256, 256, 256, 4};
    const int Tn[9] = {8, 8, 8, 8, 8, 8, 8, 8, 1};
    const float* ws[9] = {w1, w2, w3, w4, w5, w6, w7, w8, w9};

    int g = blockIdx.x * blockDim.x + threadIdx.x;
    int tile = g >> 6, lane = g & 63;
    if (tile >= 976) return;
    int layer = 0;
    while (tile >= tileStart[layer + 1]) layer++;
    int t = tile - tileStart[layer];
    int tn = Tn[layer];
    int kt = t / tn, nt = t - kt * tn;
    int k0 = kt * 16 + (lane >> 5) * 8;
    int n = nt * 32 + (lane & 31);
    const float* w = ws[layer];
    int K = Ks[layer], N = Ns[layer];
    _Float16 v[8];
#pragma unroll
    for (int j = 0; j < 8; j++) {
        int k = k0 + j;
        v[j] = (k < K && n < N) ? (_Float16)w[k * N + n] : (_Float16)0.f;
    }
    *(half8*)(dst + (size_t)tile * 512 + lane * 8) = *(half8*)v;
}

// ---------------------------------------------------------------------------
// One fused layer: C(256x256) = relu(A(256xK) @ W + b), in-place LDS->LDS,
// anti-phase schedule. AMODE 0: all-act (KT=16). 1: ksteps>=16 from x
// (L5, KT=19). 2: all-x (L1, KT=3).
// ---------------------------------------------------------------------------
template <int KT, int AMODE>
__device__ __forceinline__ void layerT(const _Float16* abuf,
                                       const _Float16* __restrict__ xbuf,
                                       const half8* __restrict__ wq,
                                       const float* __restrict__ bias,
                                       _Float16* obuf,
                                       int lane, int wave) {
    const int l31 = lane & 31, lhi = lane >> 5;
    const int grp = wave >> 2;   // anti-phase group == row half
    const int wc = wave & 3;     // col quarter
    const _Float16* aB = abuf + lhi * 2048 + (grp * 128 + l31) * 8;
    const _Float16* xB = xbuf + lhi * 2048 + (grp * 128 + l31) * 8;
    // W frag (kstep ks, n-tile wc*2+ni): wl[ks*512 + ni*64]
    const half8* wl = wq + (wc * 2) * 64 + lane;

    // Bias -> acc init: acc elem g*4+r is channel wc*64 + ni*32 + g*8 + lhi*4 + r.
    floatx16 acc[4][2];
#pragma unroll
    for (int ni = 0; ni < 2; ni++) {
        floatx16 t;
#pragma unroll
        for (int g = 0; g < 4; g++) {
            floatx4 b = *(const floatx4*)(bias + wc * 64 + ni * 32 + g * 8 + lhi * 4);
#pragma unroll
            for (int r = 0; r < 4; r++) t[g * 4 + r] = b[r];
        }
#pragma unroll
        for (int mi = 0; mi < 4; mi++) acc[mi][ni] = t;
    }

    half8 A0[4], A1[4], W0[2], W1[2];

    // A load: one kstep's 4 m-frags. base pre-offset, koff in halfs (ks*4096).
    auto LDA = [&](half8(&A)[4], const _Float16* base, int koff) {
#pragma unroll
        for (int mi = 0; mi < 4; mi++) A[mi] = *(const half8*)(base + koff + mi * 256);
    };
    auto LDW = [&](half8(&W)[2], int ks) {
#pragma unroll
        for (int ni = 0; ni < 2; ni++) W[ni] = wl[ks * 512 + ni * 64];
    };
    auto MFMA8 = [&](const half8(&A)[4], const half8(&W)[2]) {
        __builtin_amdgcn_s_setprio(1);
#pragma unroll
        for (int mi = 0; mi < 4; mi++) {
            acc[mi][0] = MF(W[0], A[mi], acc[mi][0]);
            acc[mi][1] = MF(W[1], A[mi], acc[mi][1]);
        }
        __builtin_amdgcn_s_setprio(0);
    };

    if constexpr (AMODE != 2) {
        // ---- prologue (act source) ----
        if (grp == 0) {
            LDA(A0, aB, 0); LDW(W0, 0);
            LDA(A1, aB, 4096); LDW(W1, 1);
        } else {
            LDA(A0, aB, 0); LDW(W0, 0);
        }
        // ---- main loop: phases 0..13 (k even; loads reach k+3 <= 15) ----
#pragma unroll 1
        for (int k = 0; k <= 12; k += 2) {
            // phase k (parity 0)
            if (grp == 0) MFMA8(A0, W0);
            else { LDA(A1, aB, (k + 1) * 4096); LDW(W1, k + 1); }
            BAR();
            if (grp == 0) { LDA(A0, aB, (k + 2) * 4096); LDW(W0, k + 2); }
            else MFMA8(A0, W0);
            BAR();
            // phase k+1 (parity 1)
            if (grp == 0) MFMA8(A1, W1);
            else { LDA(A0, aB, (k + 2) * 4096); LDW(W0, k + 2); }
            BAR();
            if (grp == 0) { LDA(A1, aB, (k + 3) * 4096); LDW(W1, k + 3); }
            else MFMA8(A1, W1);
            BAR();
        }
        if constexpr (AMODE == 0) {
            // ---- peel phases 14 (A0), 15 (A1); no further loads ----
            if (grp == 0) MFMA8(A0, W0);
            else { LDA(A1, aB, 15 * 4096); LDW(W1, 15); }
            BAR();
            if (grp != 0) MFMA8(A0, W0);
            BAR();
            if (grp == 0) MFMA8(A1, W1);
            BAR();
            if (grp != 0) MFMA8(A1, W1);
            BAR();
        } else {
            // ---- AMODE 1 (L5, KT=19): peel phases 14..18; ks>=16 from x ----
            // ph14 (A0)
            if (grp == 0) MFMA8(A0, W0);
            else { LDA(A1, aB, 15 * 4096); LDW(W1, 15); }
            BAR();
            if (grp == 0) { LDA(A0, xB, 0); LDW(W0, 16); }
            else MFMA8(A0, W0);
            BAR();
            // ph15 (A1)
            if (grp == 0) MFMA8(A1, W1);
            else { LDA(A0, xB, 0); LDW(W0, 16); }
            BAR();
            if (grp == 0) { LDA(A1, xB, 4096); LDW(W1, 17); }
            else MFMA8(A1, W1);
            BAR();
            // ph16 (A0 = x0)
            if (grp == 0) MFMA8(A0, W0);
            else { LDA(A1, xB, 4096); LDW(W1, 17); }
            BAR();
            if (grp == 0) { LDA(A0, xB, 8192); LDW(W0, 18); }
            else MFMA8(A0, W0);
            BAR();
            // ph17 (A1 = x1)
            if (grp == 0) MFMA8(A1, W1);
            else { LDA(A0, xB, 8192); LDW(W0, 18); }
            BAR();
            if (grp != 0) MFMA8(A1, W1);
            BAR();
            // ph18 (A0 = x2)
            if (grp == 0) MFMA8(A0, W0);
            BAR();
            if (grp != 0) MFMA8(A0, W0);
            BAR();
        }
    } else {
        // ---- AMODE 2 (L1, KT=3): all from x ----
        if (grp == 0) {
            LDA(A0, xB, 0); LDW(W0, 0);
            LDA(A1, xB, 4096); LDW(W1, 1);
        } else {
            LDA(A0, xB, 0); LDW(W0, 0);
        }
        // ph0 (A0)
        if (grp == 0) MFMA8(A0, W0);
        else { LDA(A1, xB, 4096); LDW(W1, 1); }
        BAR();
        if (grp == 0) { LDA(A0, xB, 8192); LDW(W0, 2); }
        else MFMA8(A0, W0);
        BAR();
        // ph1 (A1)
        if (grp == 0) MFMA8(A1, W1);
        else { LDA(A0, xB, 8192); LDW(W0, 2); }
        BAR();
        if (grp != 0) MFMA8(A1, W1);
        BAR();
        // ph2 (A0)
        if (grp == 0) MFMA8(A0, W0);
        BAR();
        if (grp != 0) MFMA8(A0, W0);
        BAR();
    }

    // After the final barrier all waves' act-reads are consumed -> in-place
    // writes are safe. Epilogue: relu + fp16 cvt + b64 writes.
    // row = grp*128 + mi*32 + l31; col = wc*64 + ni*32 + g*8 + lhi*4 + r
    // -> chunk = wc*8 + ni*4 + g, inner = lhi*4 + r.
#pragma unroll
    for (int mi = 0; mi < 4; mi++) {
        _Float16* ob = obuf + (grp * 128 + mi * 32 + l31) * 8 + lhi * 4;
#pragma unroll
        for (int ni = 0; ni < 2; ni++)
#pragma unroll
            for (int g = 0; g < 4; g++) {
                half4v h;
#pragma unroll
                for (int r = 0; r < 4; r++) {
                    float v = acc[mi][ni][g * 4 + r];
                    v = v > 0.f ? v : 0.f;
                    h[r] = (_Float16)v;
                }
                *(half4v*)(ob + (wc * 8 + ni * 4 + g) * 2048) = h;
            }
    }
    __syncthreads();
}

// Layer 9 (swapped): 256 -> 4 (N padded to 32). 8 waves x one 32-row m-frag;
// dual accumulators break the serial MFMA chain.
__device__ __forceinline__ void layer9T(const _Float16* abuf,
                                        const half8* __restrict__ wq,
                                        const float* __restrict__ b9,
                                        float* __restrict__ out, long r0,
                                        int lane, int wave) {
    const int l31 = lane & 31, lhi = lane >> 5;
    const _Float16* aBase = abuf + lhi * 2048 + (wave * 32 + l31) * 8;
    floatx16 acc_e = {}, acc_o = {};
    const half8* wl = wq + lane;
#pragma unroll
    for (int ks = 0; ks < 16; ks += 2) {
        half8 we = wl[ks * 64], wo = wl[(ks + 1) * 64];
        half8 ae = *(const half8*)(aBase + ks * 4096);
        half8 ao = *(const half8*)(aBase + (ks + 1) * 4096);
        acc_e = MF(we, ae, acc_e);
        acc_o = MF(wo, ao, acc_o);
    }
    if (lhi == 0) {
        floatx4 b4 = *(const floatx4*)(b9);
        floatx4 o;
#pragma unroll
        for (int r = 0; r < 4; r++) o[r] = acc_e[r] + acc_o[r] + b4[r];
        *(floatx4*)(out + (r0 + wave * 32 + l31) * 4) = o;
    }
}

__global__ __launch_bounds__(512, 2) void mlp_fused(
    const float* __restrict__ x, const _Float16* __restrict__ wpk,
    const float* __restrict__ b1, const float* __restrict__ b2,
    const float* __restrict__ b3, const float* __restrict__ b4,
    const float* __restrict__ b5, const float* __restrict__ b6,
    const float* __restrict__ b7, const float* __restrict__ b8,
    const float* __restrict__ b9, float* __restrict__ out) {
    // act 256x256 fp16 (128 KiB, in-place) + x 256x48 (24 KiB) = 152 KiB;
    // one 8-wave block per CU (LDS-limited); 2 waves/SIMD, anti-phased.
    __shared__ _Float16 lds[256 * 256 + 256 * 48];
    _Float16* buf = lds;
    _Float16* xbuf = lds + 256 * 256;
    const int tid = threadIdx.x;
    const int lane = tid & 63, wave = tid >> 6;
    const long r0 = (long)blockIdx.x * 256;

    // Stage x (chunk-major, 256-row chunks), vectorized half8 writes.
    for (int i = tid; i < 256 * 6; i += 512) {
        int row = i / 6, c = i - row * 6;
        const float* xr = x + (r0 + row) * 39 + c * 8;
        _Float16 v[8];
#pragma unroll
        for (int j = 0; j < 8; j++) {
            int col = c * 8 + j;
            v[j] = (col < 39) ? (_Float16)xr[j] : (_Float16)0.f;
        }
        *(half8*)(xbuf + c * 2048 + row * 8) = *(half8*)v;
    }
    __syncthreads();

    const half8* wp = (const half8*)wpk;  // tile = 64 half8 (1 KB)
    const half8* w1q = wp + (size_t)0 * 64;
    const half8* w2q = wp + (size_t)32 * 64;
    const half8* w3q = wp + (size_t)160 * 64;
    const half8* w4q = wp + (size_t)288 * 64;
    const half8* w5q = wp + (size_t)416 * 64;
    const half8* w6q = wp + (size_t)576 * 64;
    const half8* w7q = wp + (size_t)704 * 64;
    const half8* w8q = wp + (size_t)832 * 64;
    const half8* w9q = wp + (size_t)960 * 64;

    layerT<3, 2>(buf, xbuf, w1q, b1, buf, lane, wave);   // x -> buf (K=48)
    layerT<16, 0>(buf, xbuf, w2q, b2, buf, lane, wave);
    layerT<16, 0>(buf, xbuf, w3q, b3, buf, lane, wave);
    layerT<16, 0>(buf, xbuf, w4q, b4, buf, lane, wave);
    layerT<19, 1>(buf, xbuf, w5q, b5, buf, lane, wave);  // [h|x] skip, K=304
    layerT<16, 0>(buf, xbuf, w6q, b6, buf, lane, wave);
    layerT<16, 0>(buf, xbuf, w7q, b7, buf, lane, wave);
    layerT<16, 0>(buf, xbuf, w8q, b8, buf, lane, wave);
    layer9T(buf, w9q, b9, out, r0, lane, wave);
}

extern "C" void kernel_launch(void* const* d_in, const int* in_sizes, int n_in,
                              void* d_out, int out_size, void* d_ws, size_t ws_size,
                              hipStream_t stream) {
    const float* x = (const float*)d_in[0];
    const float* w[9];
    const float* b[9];
    for (int i = 0; i < 9; i++) {
        w[i] = (const float*)d_in[1 + 2 * i];
        b[i] = (const float*)d_in[2 + 2 * i];
    }
    _Float16* wpk = (_Float16*)d_ws;  // 999424 B

    pack_w32<<<244, 256, 0, stream>>>(w[0], w[1], w[2], w[3], w[4], w[5], w[6], w[7], w[8], wpk);
    mlp_fused<<<262144 / 256, 512, 0, stream>>>(x, wpk, b[0], b[1], b[2], b[3], b[4],
                                                b[5], b[6], b[7], b[8], (float*)d_out);
}